// Round 14
// baseline (106.033 us; speedup 1.0000x reference)
//
#include <hip/hip_runtime.h>

// Problem constants (from reference)
#define N_CELL 60000
#define N_GENE 4000
#define DIM    128
#define EPS_BN 1e-5f

#define NBUCKET 1875           // 60000/32 exactly: buckets of 32 cells (= tile)
#define CAP_H   1024           // per-bucket capacity: mean 800, +7.9 sigma
#define PBLK_I4 2048           // int4s per partition block (= 8192 edges)
#define NPART   184            // partition blocks
#define NCONV   64             // conv_w blocks
#define NYG     250            // ygene blocks (16 rows each)

// Workspace layout (4-byte words).  Zeroed region = first WS_ZERO words.
//   stats  [512]             @ 0         (sum,sumsq,mu,istd — 128 each)
//   gcur   [2048]            @ 512       (int; per-bucket counters, 1875 used)
//   --- end of zeroed region (2560 words) ---
//   preb   [N_CELL*DIM bf16] @ 2560      (3.84M w)  -> ends 3,842,560
//   ygene  [N_GENE*DIM bf16] @ 3,842,560 (256K w)   -> ends 4,098,560
//   gedges [NBUCKET*CAP_H]   @ 4,098,560 (1.92M w)  -> ends 6,018,560
//   Wb     [16384 bf16]      @ 6,018,560 (8192 w)   -> ends 6,026,752 (24.1 MB)
#define WS_STATS  0
#define WS_GCUR   512
#define WS_ZERO   2560
#define WS_PREB   2560
#define WS_YGENE  3842560
#define WS_GEDGE  4098560
#define WS_WB     6018560

typedef __bf16 bf16x8 __attribute__((ext_vector_type(8)));
typedef float  f32x4  __attribute__((ext_vector_type(4)));

__device__ __forceinline__ float bflo(unsigned int u) {
  return __uint_as_float(u << 16);
}
__device__ __forceinline__ float bfhi(unsigned int u) {
  return __uint_as_float(u & 0xFFFF0000u);
}
__device__ __forceinline__ float bf2f(unsigned short u) {
  return __uint_as_float((unsigned int)u << 16);
}
__device__ __forceinline__ unsigned short f2bf(float f) {
  const __bf16 b = (__bf16)f;
  return __builtin_bit_cast(unsigned short, b);
}

// ---------------------------------------------------------------------------
// prep_fused: three independent prep stages in ONE dispatch.
//   blocks [0,184)    : partition edges -> 1875 bucket regions (32 cells each)
//   blocks [184,248)  : conv_w (Wr fp32 -> fragment-ordered bf16)
//   blocks [248,498)  : ygene = bf16(x_gene @ Wl), 16 rows per block
// ---------------------------------------------------------------------------
__global__ __launch_bounds__(256) void prep_fused(
    const int* __restrict__ src, const int* __restrict__ dst,
    int* __restrict__ gcur, unsigned int* __restrict__ gedges,
    const float* __restrict__ wr, unsigned short* __restrict__ wb,
    const float* __restrict__ xg, const float* __restrict__ wl,
    unsigned short* __restrict__ ygene, int E) {
  __shared__ unsigned int sorted[PBLK_I4 * 4];  // 32 KB
  __shared__ int hist[2048], off[2048];         // 8 KB each
  __shared__ int cur[2048], gbase[2048];        // 8 KB each
  __shared__ int sc[256];
  __shared__ int tot;
  const int t = threadIdx.x;

  if (blockIdx.x >= NPART + NCONV) {
    // ---------------- ygene: 16 rows, 256 threads ----------------
    const int bb = blockIdx.x - (NPART + NCONV);
    const int j  = t & 127;
    const int r0 = bb * 16 + (t >> 7) * 8;
    float acc[8] = {};
    for (int k = 0; k < DIM; ++k) {
      const float w = wl[k * DIM + j];
#pragma unroll
      for (int r = 0; r < 8; ++r)
        acc[r] += xg[(size_t)(r0 + r) * DIM + k] * w;
    }
#pragma unroll
    for (int r = 0; r < 8; ++r)
      ygene[(size_t)(r0 + r) * DIM + j] = f2bf(acc[r]);
    return;
  }
  if (blockIdx.x >= NPART) {
    // ---------------- conv_w ----------------
    const int i = (blockIdx.x - NPART) * 256 + t;   // 0..16383
    const int k = i >> 7, j = i & 127;
    const int chunk = (k >> 5) * 8 + (j >> 4);
    const int lane  = ((k >> 3) & 3) * 16 + (j & 15);
    const int e     = k & 7;
    wb[(chunk * 64 + lane) * 8 + e] = f2bf(wr[i]);
    return;
  }

  // ---------------- partition (1875 buckets, bucket = dst>>5) --------------
#pragma unroll
  for (int i = 0; i < 8; ++i) hist[i * 256 + t] = 0;
  __syncthreads();

  const int n4    = E >> 2;                 // E divisible by 4 (1.5e6)
  const int base4 = blockIdx.x * PBLK_I4;
  unsigned int pk[32];
#pragma unroll
  for (int k = 0; k < 8; ++k) {
    const int i4 = base4 + k * 256 + t;
    if (i4 < n4) {
      const int4 d4 = ((const int4*)dst)[i4];
      const int4 s4 = ((const int4*)src)[i4];
      pk[k * 4 + 0] = ((unsigned)d4.x << 12) | (unsigned)s4.x;
      pk[k * 4 + 1] = ((unsigned)d4.y << 12) | (unsigned)s4.y;
      pk[k * 4 + 2] = ((unsigned)d4.z << 12) | (unsigned)s4.z;
      pk[k * 4 + 3] = ((unsigned)d4.w << 12) | (unsigned)s4.w;
#pragma unroll
      for (int j = 0; j < 4; ++j)
        atomicAdd(&hist[pk[k * 4 + j] >> 17], 1);   // bucket = dst>>5, <1875
    } else {
#pragma unroll
      for (int j = 0; j < 4; ++j) pk[k * 4 + j] = 0xFFFFFFFFu;
    }
  }
  __syncthreads();

  // ---- exclusive scan of hist[0..2047]: oct-sum + Hillis-Steele(256) ----
  int h[8];
  int qs = 0;
#pragma unroll
  for (int k = 0; k < 8; ++k) {
    h[k] = hist[8 * t + k];
    qs += h[k];
  }
  sc[t] = qs;
  __syncthreads();
#pragma unroll
  for (int o = 1; o < 256; o <<= 1) {
    const int v = (t >= o) ? sc[t - o] : 0;
    __syncthreads();
    sc[t] += v;
    __syncthreads();
  }
  {
    int run = sc[t] - qs;
#pragma unroll
    for (int k = 0; k < 8; ++k) {
      off[8 * t + k] = run;
      run += h[k];
    }
    if (t == 255) tot = sc[255];
  }
  __syncthreads();

  // ---- reserve global ranges, zero local cursors ----
#pragma unroll
  for (int i = 0; i < 8; ++i) cur[i * 256 + t] = 0;
  for (int i = t; i < 2048; i += 256)
    gbase[i] = (i < NBUCKET && hist[i] > 0) ? atomicAdd(&gcur[i], hist[i]) : 0;
  __syncthreads();

  // ---- local scatter: registers -> bucket-sorted LDS ----
#pragma unroll
  for (int k = 0; k < 32; ++k) {
    const unsigned int p = pk[k];
    if (p != 0xFFFFFFFFu) {
      const int b   = p >> 17;
      const int pos = atomicAdd(&cur[b], 1);
      sorted[off[b] + pos] = p;
    }
  }
  __syncthreads();

  // ---- coalesced-run write-out ----
  for (int j = t; j < tot; j += 256) {
    const unsigned int p = sorted[j];
    const int b   = p >> 17;
    const int idx = gbase[b] + (j - off[b]);
    if (idx < CAP_H) gedges[(size_t)b * CAP_H + idx] = p;
  }
}

// ---------------------------------------------------------------------------
// gemm_fused, R14: one block per 32-cell tile (1875 blocks; R13's 64-cell
// version was occupancy-bound — 40 KB LDS -> 4 blk/CU -> 50% wave ceiling,
// 28% measured, 1/3-round tail).  Now ~20 KB LDS -> 7 blk/CU (~87% ceiling),
// 7.3 rounds (4.5% tail).  Phases unchanged:
//   P1 LDS counting sort (32 counters) -> P2 bf16 gather -> P3 A-stage+MFMA
//   -> P4 in-place epilogue + BN shfl sums -> P5 vectorized store + atomics.
// ---------------------------------------------------------------------------
__global__ __launch_bounds__(256) void gemm_fused(
    const unsigned int* __restrict__ gedges, const int* __restrict__ gcur,
    const unsigned short* __restrict__ yb, const float* __restrict__ xc,
    const unsigned short* __restrict__ wb, const float* __restrict__ bl,
    unsigned short* __restrict__ preb, float* __restrict__ stats) {
  // region: [0,4096) u16 = A-stage (8 KB); [4096,5120) u16 = srt (2 KB).
  __shared__ unsigned short region[5120];
  __shared__ unsigned short msg_lds[32 * 136];   // 8.7 KB
  __shared__ int counts[32], coff[32], ccur[32], sc32[32];
  __shared__ float ps[4][32], ps2[4][32];
  unsigned short* a_lds = region;
  unsigned short* srt   = region + 4096;

  const int b    = blockIdx.x;
  const int t    = threadIdx.x;
  const int row0 = b * 32;          // 32 | 60000: no partial tiles

  int cnt = gcur[b];
  if (cnt > CAP_H) cnt = CAP_H;

  if (t < 32) { counts[t] = 0; ccur[t] = 0; }
  __syncthreads();

  // ---- P1a: stage edges into registers + per-cell histogram ----
  unsigned int e[4];                             // 4*256 = 1024 = CAP_H
#pragma unroll
  for (int k = 0; k < 4; ++k) {
    const int j = k * 256 + t;
    e[k] = (j < cnt) ? gedges[(size_t)b * CAP_H + j] : 0xFFFFFFFFu;
    if (e[k] != 0xFFFFFFFFu) atomicAdd(&counts[(e[k] >> 12) & 31], 1);
  }
  __syncthreads();

  // ---- P1b: exclusive scan of counts[32] ----
  if (t < 32) sc32[t] = counts[t];
  __syncthreads();
#pragma unroll
  for (int o = 1; o < 32; o <<= 1) {
    int v = 0;
    if (t < 32 && t >= o) v = sc32[t - o];
    __syncthreads();
    if (t < 32) sc32[t] += v;
    __syncthreads();
  }
  if (t < 32) coff[t] = sc32[t] - counts[t];
  __syncthreads();

  // ---- P1c: scatter src indices into cell-sorted srt (u16) ----
#pragma unroll
  for (int k = 0; k < 4; ++k) {
    if (e[k] != 0xFFFFFFFFu) {
      const int c   = (e[k] >> 12) & 31;
      const int pos = atomicAdd(&ccur[c], 1);
      srt[coff[c] + pos] = (unsigned short)(e[k] & 0xFFF);
    }
  }
  __syncthreads();

  // ---- P2: bf16 gather; wave w owns cells [w*8, w*8+8) ----
  const int w    = t >> 6;
  const int l    = t & 63;
  const int grp  = l >> 4;                       // edge group 0..3
  const int lsub = l & 15;                       // 8-dim slice
  for (int ci = 0; ci < 8; ++ci) {
    const int c     = w * 8 + ci;
    const int gcell = row0 + c;
    const int beg = coff[c], num = counts[c];

    float a0[8] = {}, a1[8] = {};
    int ei = grp;
    for (; ei + 4 < num; ei += 8) {              // 2-deep, 4 groups
      const int s0 = srt[beg + ei];
      const int s1 = srt[beg + ei + 4];
      const uint4 v0 = *(const uint4*)(yb + (size_t)s0 * DIM + lsub * 8);
      const uint4 v1 = *(const uint4*)(yb + (size_t)s1 * DIM + lsub * 8);
      a0[0] += bflo(v0.x); a0[1] += bfhi(v0.x);
      a0[2] += bflo(v0.y); a0[3] += bfhi(v0.y);
      a0[4] += bflo(v0.z); a0[5] += bfhi(v0.z);
      a0[6] += bflo(v0.w); a0[7] += bfhi(v0.w);
      a1[0] += bflo(v1.x); a1[1] += bfhi(v1.x);
      a1[2] += bflo(v1.y); a1[3] += bfhi(v1.y);
      a1[4] += bflo(v1.z); a1[5] += bfhi(v1.z);
      a1[6] += bflo(v1.w); a1[7] += bfhi(v1.w);
    }
    if (ei < num) {                              // tail edge for this group
      const int s = srt[beg + ei];
      const uint4 v = *(const uint4*)(yb + (size_t)s * DIM + lsub * 8);
      a0[0] += bflo(v.x); a0[1] += bfhi(v.x);
      a0[2] += bflo(v.y); a0[3] += bfhi(v.y);
      a0[4] += bflo(v.z); a0[5] += bfhi(v.z);
      a0[6] += bflo(v.w); a0[7] += bfhi(v.w);
    }
    float r[8];
#pragma unroll
    for (int d = 0; d < 8; ++d) {
      float s = a0[d] + a1[d];
      s += __shfl_xor(s, 16);
      s += __shfl_xor(s, 32);
      r[d] = s;
    }
    if (grp == 0) {
      const float ic = 1.0f / fmaxf((float)num, 1.0f);
      const unsigned int o0 =
          ((unsigned int)f2bf(r[1] * ic) << 16) | f2bf(r[0] * ic);
      const unsigned int o1 =
          ((unsigned int)f2bf(r[3] * ic) << 16) | f2bf(r[2] * ic);
      const unsigned int o2 =
          ((unsigned int)f2bf(r[5] * ic) << 16) | f2bf(r[4] * ic);
      const unsigned int o3 =
          ((unsigned int)f2bf(r[7] * ic) << 16) | f2bf(r[6] * ic);
      *(uint4*)&msg_lds[c * 136 + lsub * 8] = make_uint4(o0, o1, o2, o3);
    }
    (void)gcell;
  }

  // ---- P3a: stage A (fp32 -> bf16, XOR-swizzled); srt is dead now ----
  {
    const int row = t >> 3;                      // 0..31
    const int h   = t & 7;                       // K-eighth (16 elems)
    const float* xrow = xc + (size_t)(row0 + row) * DIM;
    const int kk = h * 16;
    const float4 f0 = *(const float4*)(xrow + kk);
    const float4 f1 = *(const float4*)(xrow + kk + 4);
    const float4 f2 = *(const float4*)(xrow + kk + 8);
    const float4 f3 = *(const float4*)(xrow + kk + 12);
    const float fv[16] = {f0.x, f0.y, f0.z, f0.w, f1.x, f1.y, f1.z, f1.w,
                          f2.x, f2.y, f2.z, f2.w, f3.x, f3.y, f3.z, f3.w};
    union { unsigned short u[16]; uint4 q[2]; } pk;
#pragma unroll
    for (int q = 0; q < 16; ++q) pk.u[q] = f2bf(fv[q]);
    const int s0 = ((kk >> 3) + 0) ^ (row & 15);
    const int s1 = ((kk >> 3) + 1) ^ (row & 15);
    *(uint4*)&a_lds[row * 128 + s0 * 8] = pk.q[0];
    *(uint4*)&a_lds[row * 128 + s1 * 8] = pk.q[1];
  }
  __syncthreads();   // A + msg_lds visible to all

  // ---- P3b: MFMA; wave w owns cols [w*32, w*32+32), rows 0..31 ----
  const int l15 = l & 15, lq = l >> 4;
  f32x4 acc[2][2];
#pragma unroll
  for (int g = 0; g < 2; ++g)
#pragma unroll
    for (int c = 0; c < 2; ++c) acc[g][c] = (f32x4){0.f, 0.f, 0.f, 0.f};

#pragma unroll
  for (int ks = 0; ks < 4; ++ks) {
    bf16x8 bfr[2];
#pragma unroll
    for (int c = 0; c < 2; ++c) {
      const int cf = w * 2 + c;
      bfr[c] = *(const bf16x8*)(wb + (size_t)(((ks * 8 + cf) * 64 + l) * 8));
    }
    bf16x8 afr[2];
#pragma unroll
    for (int g = 0; g < 2; ++g) {
      const int row = g * 16 + l15;
      const int s   = (ks * 4 + lq) ^ l15;
      afr[g] = *(const bf16x8*)&a_lds[row * 128 + s * 8];
    }
#pragma unroll
    for (int g = 0; g < 2; ++g)
#pragma unroll
      for (int c = 0; c < 2; ++c)
        acc[g][c] = __builtin_amdgcn_mfma_f32_16x16x32_bf16(
            afr[g], bfr[c], acc[g][c], 0, 0, 0);
  }

  // ---- P4: val = acc + msg + bias, in-place into msg_lds; BN sums ----
  float csum[2] = {0.f, 0.f}, csq[2] = {0.f, 0.f};
#pragma unroll
  for (int g = 0; g < 2; ++g) {
#pragma unroll
    for (int c = 0; c < 2; ++c) {
      const int col = (w * 2 + c) * 16 + l15;
      const float bbl = bl[col];
#pragma unroll
      for (int r = 0; r < 4; ++r) {
        const int row = g * 16 + lq * 4 + r;
        const int idx = row * 136 + col;
        const float val = acc[g][c][r] + bf2f(msg_lds[idx]) + bbl;
        msg_lds[idx] = f2bf(val);
        csum[c] += val;
        csq[c]  += val * val;
      }
    }
  }
#pragma unroll
  for (int c = 0; c < 2; ++c) {
    csum[c] += __shfl_xor(csum[c], 16);
    csum[c] += __shfl_xor(csum[c], 32);
    csq[c]  += __shfl_xor(csq[c], 16);
    csq[c]  += __shfl_xor(csq[c], 32);
  }
  if (lq == 0) {
#pragma unroll
    for (int c = 0; c < 2; ++c) {
      ps[w][c * 16 + l15]  = csum[c];   // col = w*32 + c*16 + l15
      ps2[w][c * 16 + l15] = csq[c];
    }
  }
  __syncthreads();

  // ---- P5: vectorized store msg_lds -> preb; BN atomics ----
  {
    const int row = t & 31;
    const int cg  = t >> 5;                      // 8 col-groups of 16
    const int grow = row0 + row;
    unsigned short* prow = preb + (size_t)grow * DIM + cg * 16;
    const unsigned short* mrow = msg_lds + row * 136 + cg * 16;
    *(uint4*)(prow)     = *(const uint4*)(mrow);
    *(uint4*)(prow + 8) = *(const uint4*)(mrow + 8);

    const int which = t >> 7;          // 0: sum, 1: sumsq
    const int col   = t & 127;
    const int wi    = col >> 5;
    const int idx   = col & 31;
    const float v = which ? ps2[wi][idx] : ps[wi][idx];
    unsafeAtomicAdd(&stats[t], v);     // t in [0,256)
  }
}

// ---------------------------------------------------------------------------
// bn_finalize: mu / inv_std from accumulated sums (1 block, ~2 us)
// ---------------------------------------------------------------------------
__global__ __launch_bounds__(128) void bn_finalize(float* __restrict__ stats) {
  const int j = threadIdx.x;
  const float mu  = stats[j] / (float)N_CELL;
  const float var = stats[128 + j] / (float)N_CELL - mu * mu;
  stats[256 + j] = mu;
  stats[384 + j] = rsqrtf(var + EPS_BN);
}

// ---------------------------------------------------------------------------
// bn_apply: read bf16 pre (L2/L3-hot), write fp32 out
// ---------------------------------------------------------------------------
__global__ __launch_bounds__(256) void bn_apply(
    const unsigned short* __restrict__ preb, float* __restrict__ out,
    const float* __restrict__ stats) {
  const size_t total = (size_t)N_CELL * DIM / 8;
  const size_t step  = (size_t)gridDim.x * blockDim.x;
  for (size_t i = (size_t)blockIdx.x * blockDim.x + threadIdx.x; i < total;
       i += step) {
    const uint4 v = ((const uint4*)preb)[i];
    const int col = (int)((i * 8) & (DIM - 1));
    const float* mu = stats + 256 + col;
    const float* is = stats + 384 + col;
    float4 o0, o1;
    o0.x = (bflo(v.x) - mu[0]) * is[0];
    o0.y = (bfhi(v.x) - mu[1]) * is[1];
    o0.z = (bflo(v.y) - mu[2]) * is[2];
    o0.w = (bfhi(v.y) - mu[3]) * is[3];
    o1.x = (bflo(v.z) - mu[4]) * is[4];
    o1.y = (bfhi(v.z) - mu[5]) * is[5];
    o1.z = (bflo(v.w) - mu[6]) * is[6];
    o1.w = (bfhi(v.w) - mu[7]) * is[7];
    *(float4*)(out + i * 8)     = o0;
    *(float4*)(out + i * 8 + 4) = o1;
  }
}

// ---------------------------------------------------------------------------
extern "C" void kernel_launch(void* const* d_in, const int* in_sizes, int n_in,
                              void* d_out, int out_size, void* d_ws,
                              size_t ws_size, hipStream_t stream) {
  const float* x_cell = (const float*)d_in[0];
  const float* x_gene = (const float*)d_in[1];
  const float* Wl_gc  = (const float*)d_in[2];
  const float* bl_gc  = (const float*)d_in[3];
  const float* Wr_gc  = (const float*)d_in[4];
  // d_in[5..7] (cg weights) are dead: the gene branch never feeds the output.
  const int* gc_src = (const int*)d_in[8];
  const int* gc_dst = (const int*)d_in[9];
  const int  E      = in_sizes[8];

  const float* Wl1 = Wl_gc + DIM * DIM;   // layer 1 (last)
  const float* bl1 = bl_gc + DIM;
  const float* Wr1 = Wr_gc + DIM * DIM;

  float* ws    = (float*)d_ws;
  float* stats = ws + WS_STATS;
  int*   gcur  = (int*)(ws + WS_GCUR);
  unsigned short* preb   = (unsigned short*)(ws + WS_PREB);
  unsigned short* ygene  = (unsigned short*)(ws + WS_YGENE);
  unsigned int*   gedges = (unsigned int*)(ws + WS_GEDGE);
  unsigned short* Wb     = (unsigned short*)(ws + WS_WB);
  float* out   = (float*)d_out;

  // zero stats + bucket counters (10 KB)
  hipMemsetAsync(d_ws, 0, (size_t)WS_ZERO * sizeof(float), stream);

  prep_fused<<<NPART + NCONV + NYG, 256, 0, stream>>>(
      gc_src, gc_dst, gcur, gedges, Wr1, Wb, x_gene, Wl1, ygene, E);

  gemm_fused<<<NBUCKET, 256, 0, stream>>>(gedges, gcur, ygene, x_cell, Wb,
                                          bl1, preb, stats);

  bn_finalize<<<1, 128, 0, stream>>>(stats);
  bn_apply<<<2048, 256, 0, stream>>>(preb, out, stats);
}

// Round 15
// 98.652 us; speedup vs baseline: 1.0748x; 1.0748x over previous
//
#include <hip/hip_runtime.h>

// Problem constants (from reference)
#define N_CELL 60000
#define N_GENE 4000
#define DIM    128
#define EPS_BN 1e-5f

#define NBUCKET 938            // ceil(60000/64) buckets of 64 cells (= tile)
#define CAP_H   2048           // per-bucket capacity: mean 1600, +11 sigma
#define PBLK_I4 2048           // int4s per partition block (= 8192 edges)
#define NPART   184            // partition blocks
#define NCONV   64             // conv_w blocks
#define NYG     250            // ygene blocks (16 rows each)

// Workspace layout (4-byte words).  Zeroed region = first WS_ZERO words.
//   stats  [512]             @ 0         (sum,sumsq,mu,istd — 128 each)
//   gcur   [1024]            @ 512       (int; per-bucket counters, 938 used)
//   --- end of zeroed region (2048 words) ---
//   preb   [N_CELL*DIM bf16] @ 2048      (3.84M w)  -> ends 3,842,048
//   ygene  [N_GENE*DIM bf16] @ 3,842,048 (256K w)   -> ends 4,098,048
//   gedges [NBUCKET*CAP_H]   @ 4,098,048 (1.92M w)  -> ends 6,019,072
//   Wb     [16384 bf16]      @ 6,019,072 (8192 w)   -> ends 6,027,264 (24.1 MB)
#define WS_STATS  0
#define WS_GCUR   512
#define WS_ZERO   2048
#define WS_PREB   2048
#define WS_YGENE  3842048
#define WS_GEDGE  4098048
#define WS_WB     6019072

typedef __bf16 bf16x8 __attribute__((ext_vector_type(8)));
typedef float  f32x4  __attribute__((ext_vector_type(4)));

__device__ __forceinline__ float bflo(unsigned int u) {
  return __uint_as_float(u << 16);
}
__device__ __forceinline__ float bfhi(unsigned int u) {
  return __uint_as_float(u & 0xFFFF0000u);
}
__device__ __forceinline__ float bf2f(unsigned short u) {
  return __uint_as_float((unsigned int)u << 16);
}
__device__ __forceinline__ unsigned short f2bf(float f) {
  const __bf16 b = (__bf16)f;
  return __builtin_bit_cast(unsigned short, b);
}

// ---------------------------------------------------------------------------
// prep_fused: three independent prep stages in ONE dispatch (R13 version).
//   blocks [0,184)    : partition edges -> 938 bucket regions (64 cells each)
//   blocks [184,248)  : conv_w (Wr fp32 -> fragment-ordered bf16)
//   blocks [248,498)  : ygene = bf16(x_gene @ Wl), 16 rows per block
// ---------------------------------------------------------------------------
__global__ __launch_bounds__(256) void prep_fused(
    const int* __restrict__ src, const int* __restrict__ dst,
    int* __restrict__ gcur, unsigned int* __restrict__ gedges,
    const float* __restrict__ wr, unsigned short* __restrict__ wb,
    const float* __restrict__ xg, const float* __restrict__ wl,
    unsigned short* __restrict__ ygene, int E) {
  __shared__ unsigned int sorted[PBLK_I4 * 4];  // 32 KB
  __shared__ int hist[1024], off[1024];
  __shared__ int cur[1024], gbase[1024];
  __shared__ int sc[256];
  __shared__ int tot;
  const int t = threadIdx.x;

  if (blockIdx.x >= NPART + NCONV) {
    // ---------------- ygene: 16 rows, 256 threads ----------------
    const int bb = blockIdx.x - (NPART + NCONV);
    const int j  = t & 127;
    const int r0 = bb * 16 + (t >> 7) * 8;
    float acc[8] = {};
    for (int k = 0; k < DIM; ++k) {
      const float w = wl[k * DIM + j];
#pragma unroll
      for (int r = 0; r < 8; ++r)
        acc[r] += xg[(size_t)(r0 + r) * DIM + k] * w;
    }
#pragma unroll
    for (int r = 0; r < 8; ++r)
      ygene[(size_t)(r0 + r) * DIM + j] = f2bf(acc[r]);
    return;
  }
  if (blockIdx.x >= NPART) {
    // ---------------- conv_w ----------------
    const int i = (blockIdx.x - NPART) * 256 + t;   // 0..16383
    const int k = i >> 7, j = i & 127;
    const int chunk = (k >> 5) * 8 + (j >> 4);
    const int lane  = ((k >> 3) & 3) * 16 + (j & 15);
    const int e     = k & 7;
    wb[(chunk * 64 + lane) * 8 + e] = f2bf(wr[i]);
    return;
  }

  // ---------------- partition (938 buckets, bucket = dst>>6) ----------------
  hist[t] = 0; hist[256 + t] = 0; hist[512 + t] = 0; hist[768 + t] = 0;
  __syncthreads();

  const int n4    = E >> 2;                 // E divisible by 4 (1.5e6)
  const int base4 = blockIdx.x * PBLK_I4;
  unsigned int pk[32];
#pragma unroll
  for (int k = 0; k < 8; ++k) {
    const int i4 = base4 + k * 256 + t;
    if (i4 < n4) {
      const int4 d4 = ((const int4*)dst)[i4];
      const int4 s4 = ((const int4*)src)[i4];
      pk[k * 4 + 0] = ((unsigned)d4.x << 12) | (unsigned)s4.x;
      pk[k * 4 + 1] = ((unsigned)d4.y << 12) | (unsigned)s4.y;
      pk[k * 4 + 2] = ((unsigned)d4.z << 12) | (unsigned)s4.z;
      pk[k * 4 + 3] = ((unsigned)d4.w << 12) | (unsigned)s4.w;
#pragma unroll
      for (int j = 0; j < 4; ++j)
        atomicAdd(&hist[pk[k * 4 + j] >> 18], 1);   // bucket = dst>>6, <938
    } else {
#pragma unroll
      for (int j = 0; j < 4; ++j) pk[k * 4 + j] = 0xFFFFFFFFu;
    }
  }
  __syncthreads();

  // ---- exclusive scan of hist[0..1023]: quad-sum + Hillis-Steele(256) ----
  const int h0 = hist[4 * t], h1 = hist[4 * t + 1];
  const int h2 = hist[4 * t + 2], h3 = hist[4 * t + 3];
  const int qs = h0 + h1 + h2 + h3;
  sc[t] = qs;
  __syncthreads();
#pragma unroll
  for (int o = 1; o < 256; o <<= 1) {
    const int v = (t >= o) ? sc[t - o] : 0;
    __syncthreads();
    sc[t] += v;
    __syncthreads();
  }
  {
    const int excl = sc[t] - qs;
    off[4 * t]     = excl;
    off[4 * t + 1] = excl + h0;
    off[4 * t + 2] = excl + h0 + h1;
    off[4 * t + 3] = excl + h0 + h1 + h2;
    if (t == 255) tot = sc[255];
  }
  __syncthreads();

  // ---- reserve global ranges, zero local cursors ----
  cur[t] = 0; cur[256 + t] = 0; cur[512 + t] = 0; cur[768 + t] = 0;
  for (int i = t; i < 1024; i += 256)
    gbase[i] = (i < NBUCKET && hist[i] > 0) ? atomicAdd(&gcur[i], hist[i]) : 0;
  __syncthreads();

  // ---- local scatter: registers -> bucket-sorted LDS ----
#pragma unroll
  for (int k = 0; k < 32; ++k) {
    const unsigned int p = pk[k];
    if (p != 0xFFFFFFFFu) {
      const int b   = p >> 18;
      const int pos = atomicAdd(&cur[b], 1);
      sorted[off[b] + pos] = p;
    }
  }
  __syncthreads();

  // ---- coalesced-run write-out ----
  for (int j = t; j < tot; j += 256) {
    const unsigned int p = sorted[j];
    const int b   = p >> 18;
    const int idx = gbase[b] + (j - off[b]);
    if (idx < CAP_H) gedges[(size_t)b * CAP_H + idx] = p;
  }
}

// ---------------------------------------------------------------------------
// gemm_fused, R15: 64-cell tile (R13 amortization) WITHOUT the A-stage LDS.
// The 16x16x32 A-fragment is lane-contiguous in k (lane (lq,l15): row l15,
// k = ks*32 + lq*8..+8 = 32 B) -> load A straight from global x_cell (two
// float4 per fragment, fp32->bf16 in registers; the 32 KB tile is L1-shared
// by the 4 waves).  Deletes a_lds (16 KB) + one phase + one barrier:
// LDS 40 KB -> ~23.5 KB -> 6 blocks/CU -> all 938 blocks co-resident
// (R13 ran 3.66 sequential rounds of 4 blocks/CU; R14 showed smaller tiles
// lose to per-block fixed cost, so tile stays 64).
//   P1 LDS counting sort -> P2 bf16 gather -> barrier -> P3 MFMA (A,B global)
//   -> P4 in-place epilogue + BN shfl sums -> P5 vectorized store + atomics.
// ---------------------------------------------------------------------------
__global__ __launch_bounds__(256) void gemm_fused(
    const unsigned int* __restrict__ gedges, const int* __restrict__ gcur,
    const unsigned short* __restrict__ yb, const float* __restrict__ xc,
    const unsigned short* __restrict__ wb, const float* __restrict__ bl,
    unsigned short* __restrict__ preb, float* __restrict__ stats) {
  __shared__ unsigned short srt[CAP_H];          // 4 KB, cell-sorted src ids
  __shared__ unsigned short msg_lds[64 * 136];   // 17.4 KB
  __shared__ int counts[64], coff[64], ccur[64], sc64[64];
  __shared__ float ps[4][32], ps2[4][32];

  const int b    = blockIdx.x;
  const int t    = threadIdx.x;
  const int row0 = b * 64;

  int cnt = gcur[b];
  if (cnt > CAP_H) cnt = CAP_H;

  if (t < 64) { counts[t] = 0; ccur[t] = 0; }
  __syncthreads();

  // ---- P1a: stage edges into registers + per-cell histogram ----
  unsigned int e[8];                             // 8*256 = 2048 = CAP_H
#pragma unroll
  for (int k = 0; k < 8; ++k) {
    const int j = k * 256 + t;
    e[k] = (j < cnt) ? gedges[(size_t)b * CAP_H + j] : 0xFFFFFFFFu;
    if (e[k] != 0xFFFFFFFFu) atomicAdd(&counts[(e[k] >> 12) & 63], 1);
  }
  __syncthreads();

  // ---- P1b: exclusive scan of counts[64] ----
  if (t < 64) sc64[t] = counts[t];
  __syncthreads();
#pragma unroll
  for (int o = 1; o < 64; o <<= 1) {
    int v = 0;
    if (t < 64 && t >= o) v = sc64[t - o];
    __syncthreads();
    if (t < 64) sc64[t] += v;
    __syncthreads();
  }
  if (t < 64) coff[t] = sc64[t] - counts[t];
  __syncthreads();

  // ---- P1c: scatter src indices into cell-sorted srt (u16) ----
#pragma unroll
  for (int k = 0; k < 8; ++k) {
    if (e[k] != 0xFFFFFFFFu) {
      const int c   = (e[k] >> 12) & 63;
      const int pos = atomicAdd(&ccur[c], 1);
      srt[coff[c] + pos] = (unsigned short)(e[k] & 0xFFF);
    }
  }
  __syncthreads();

  // ---- P2: bf16 gather; wave w owns cells [w*16, w*16+16) ----
  const int w    = t >> 6;
  const int l    = t & 63;
  const int grp  = l >> 4;                       // edge group 0..3
  const int lsub = l & 15;                       // 8-dim slice
  for (int ci = 0; ci < 16; ++ci) {
    const int c     = w * 16 + ci;
    const int gcell = row0 + c;
    if (gcell >= N_CELL) break;                  // wave-uniform (cells ascend)
    const int beg = coff[c], num = counts[c];

    float a0[8] = {}, a1[8] = {};
    int ei = grp;
    for (; ei + 4 < num; ei += 8) {              // 2-deep, 4 groups
      const int s0 = srt[beg + ei];
      const int s1 = srt[beg + ei + 4];
      const uint4 v0 = *(const uint4*)(yb + (size_t)s0 * DIM + lsub * 8);
      const uint4 v1 = *(const uint4*)(yb + (size_t)s1 * DIM + lsub * 8);
      a0[0] += bflo(v0.x); a0[1] += bfhi(v0.x);
      a0[2] += bflo(v0.y); a0[3] += bfhi(v0.y);
      a0[4] += bflo(v0.z); a0[5] += bfhi(v0.z);
      a0[6] += bflo(v0.w); a0[7] += bfhi(v0.w);
      a1[0] += bflo(v1.x); a1[1] += bfhi(v1.x);
      a1[2] += bflo(v1.y); a1[3] += bfhi(v1.y);
      a1[4] += bflo(v1.z); a1[5] += bfhi(v1.z);
      a1[6] += bflo(v1.w); a1[7] += bfhi(v1.w);
    }
    if (ei < num) {                              // tail edge for this group
      const int s = srt[beg + ei];
      const uint4 v = *(const uint4*)(yb + (size_t)s * DIM + lsub * 8);
      a0[0] += bflo(v.x); a0[1] += bfhi(v.x);
      a0[2] += bflo(v.y); a0[3] += bfhi(v.y);
      a0[4] += bflo(v.z); a0[5] += bfhi(v.z);
      a0[6] += bflo(v.w); a0[7] += bfhi(v.w);
    }
    float r[8];
#pragma unroll
    for (int d = 0; d < 8; ++d) {
      float s = a0[d] + a1[d];
      s += __shfl_xor(s, 16);
      s += __shfl_xor(s, 32);
      r[d] = s;
    }
    if (grp == 0) {
      const float ic = 1.0f / fmaxf((float)num, 1.0f);
      const unsigned int o0 =
          ((unsigned int)f2bf(r[1] * ic) << 16) | f2bf(r[0] * ic);
      const unsigned int o1 =
          ((unsigned int)f2bf(r[3] * ic) << 16) | f2bf(r[2] * ic);
      const unsigned int o2 =
          ((unsigned int)f2bf(r[5] * ic) << 16) | f2bf(r[4] * ic);
      const unsigned int o3 =
          ((unsigned int)f2bf(r[7] * ic) << 16) | f2bf(r[6] * ic);
      *(uint4*)&msg_lds[c * 136 + lsub * 8] = make_uint4(o0, o1, o2, o3);
    }
  }
  __syncthreads();   // msg_lds complete before P4 reads

  // ---- P3: MFMA; A-fragments straight from global (L1-shared) ----
  const int l15 = l & 15, lq = l >> 4;
  f32x4 acc[4][2];
#pragma unroll
  for (int g = 0; g < 4; ++g)
#pragma unroll
    for (int c = 0; c < 2; ++c) acc[g][c] = (f32x4){0.f, 0.f, 0.f, 0.f};

#pragma unroll
  for (int ks = 0; ks < 4; ++ks) {
    bf16x8 bfr[2];
#pragma unroll
    for (int c = 0; c < 2; ++c) {
      const int cf = w * 2 + c;
      bfr[c] = *(const bf16x8*)(wb + (size_t)(((ks * 8 + cf) * 64 + l) * 8));
    }
#pragma unroll
    for (int g = 0; g < 4; ++g) {
      if (row0 + g * 16 < N_CELL) {              // wave-uniform (60000%16==0)
        const float* ap =
            xc + (size_t)(row0 + g * 16 + l15) * DIM + ks * 32 + lq * 8;
        const float4 fa = *(const float4*)ap;
        const float4 fb = *(const float4*)(ap + 4);
        union { unsigned short u[8]; bf16x8 v; } af;
        af.u[0] = f2bf(fa.x); af.u[1] = f2bf(fa.y);
        af.u[2] = f2bf(fa.z); af.u[3] = f2bf(fa.w);
        af.u[4] = f2bf(fb.x); af.u[5] = f2bf(fb.y);
        af.u[6] = f2bf(fb.z); af.u[7] = f2bf(fb.w);
#pragma unroll
        for (int c = 0; c < 2; ++c)
          acc[g][c] = __builtin_amdgcn_mfma_f32_16x16x32_bf16(
              af.v, bfr[c], acc[g][c], 0, 0, 0);
      }
    }
  }

  // ---- P4: val = acc + msg + bias, in-place into msg_lds; BN sums ----
  float csum[2] = {0.f, 0.f}, csq[2] = {0.f, 0.f};
#pragma unroll
  for (int g = 0; g < 4; ++g) {
#pragma unroll
    for (int c = 0; c < 2; ++c) {
      const int col = (w * 2 + c) * 16 + l15;
      const float bbl = bl[col];
#pragma unroll
      for (int r = 0; r < 4; ++r) {
        const int row  = g * 16 + lq * 4 + r;
        const int grow = row0 + row;
        if (grow < N_CELL) {
          const int idx = row * 136 + col;
          const float val = acc[g][c][r] + bf2f(msg_lds[idx]) + bbl;
          msg_lds[idx] = f2bf(val);
          csum[c] += val;
          csq[c]  += val * val;
        }
      }
    }
  }
#pragma unroll
  for (int c = 0; c < 2; ++c) {
    csum[c] += __shfl_xor(csum[c], 16);
    csum[c] += __shfl_xor(csum[c], 32);
    csq[c]  += __shfl_xor(csq[c], 16);
    csq[c]  += __shfl_xor(csq[c], 32);
  }
  if (lq == 0) {
#pragma unroll
    for (int c = 0; c < 2; ++c) {
      ps[w][c * 16 + l15]  = csum[c];   // col = w*32 + c*16 + l15
      ps2[w][c * 16 + l15] = csq[c];
    }
  }
  __syncthreads();

  // ---- P5: vectorized store msg_lds -> preb; BN atomics ----
  {
    const int grow = row0 + l;
    if (grow < N_CELL) {
      unsigned short* prow = preb + (size_t)grow * DIM + w * 32;
      const unsigned short* mrow = msg_lds + l * 136 + w * 32;
#pragma unroll
      for (int i = 0; i < 4; ++i)
        *(uint4*)(prow + i * 8) = *(const uint4*)(mrow + i * 8);
    }
    const int which = t >> 7;          // 0: sum, 1: sumsq
    const int col   = t & 127;
    const int wi    = col >> 5;
    const int idx   = col & 31;
    const float v = which ? ps2[wi][idx] : ps[wi][idx];
    unsafeAtomicAdd(&stats[t], v);     // t in [0,256)
  }
}

// ---------------------------------------------------------------------------
// bn_finalize: mu / inv_std from accumulated sums (1 block, ~2 us)
// ---------------------------------------------------------------------------
__global__ __launch_bounds__(128) void bn_finalize(float* __restrict__ stats) {
  const int j = threadIdx.x;
  const float mu  = stats[j] / (float)N_CELL;
  const float var = stats[128 + j] / (float)N_CELL - mu * mu;
  stats[256 + j] = mu;
  stats[384 + j] = rsqrtf(var + EPS_BN);
}

// ---------------------------------------------------------------------------
// bn_apply: read bf16 pre (L2/L3-hot), write fp32 out
// ---------------------------------------------------------------------------
__global__ __launch_bounds__(256) void bn_apply(
    const unsigned short* __restrict__ preb, float* __restrict__ out,
    const float* __restrict__ stats) {
  const size_t total = (size_t)N_CELL * DIM / 8;
  const size_t step  = (size_t)gridDim.x * blockDim.x;
  for (size_t i = (size_t)blockIdx.x * blockDim.x + threadIdx.x; i < total;
       i += step) {
    const uint4 v = ((const uint4*)preb)[i];
    const int col = (int)((i * 8) & (DIM - 1));
    const float* mu = stats + 256 + col;
    const float* is = stats + 384 + col;
    float4 o0, o1;
    o0.x = (bflo(v.x) - mu[0]) * is[0];
    o0.y = (bfhi(v.x) - mu[1]) * is[1];
    o0.z = (bflo(v.y) - mu[2]) * is[2];
    o0.w = (bfhi(v.y) - mu[3]) * is[3];
    o1.x = (bflo(v.z) - mu[4]) * is[4];
    o1.y = (bfhi(v.z) - mu[5]) * is[5];
    o1.z = (bflo(v.w) - mu[6]) * is[6];
    o1.w = (bfhi(v.w) - mu[7]) * is[7];
    *(float4*)(out + i * 8)     = o0;
    *(float4*)(out + i * 8 + 4) = o1;
  }
}

// ---------------------------------------------------------------------------
extern "C" void kernel_launch(void* const* d_in, const int* in_sizes, int n_in,
                              void* d_out, int out_size, void* d_ws,
                              size_t ws_size, hipStream_t stream) {
  const float* x_cell = (const float*)d_in[0];
  const float* x_gene = (const float*)d_in[1];
  const float* Wl_gc  = (const float*)d_in[2];
  const float* bl_gc  = (const float*)d_in[3];
  const float* Wr_gc  = (const float*)d_in[4];
  // d_in[5..7] (cg weights) are dead: the gene branch never feeds the output.
  const int* gc_src = (const int*)d_in[8];
  const int* gc_dst = (const int*)d_in[9];
  const int  E      = in_sizes[8];

  const float* Wl1 = Wl_gc + DIM * DIM;   // layer 1 (last)
  const float* bl1 = bl_gc + DIM;
  const float* Wr1 = Wr_gc + DIM * DIM;

  float* ws    = (float*)d_ws;
  float* stats = ws + WS_STATS;
  int*   gcur  = (int*)(ws + WS_GCUR);
  unsigned short* preb   = (unsigned short*)(ws + WS_PREB);
  unsigned short* ygene  = (unsigned short*)(ws + WS_YGENE);
  unsigned int*   gedges = (unsigned int*)(ws + WS_GEDGE);
  unsigned short* Wb     = (unsigned short*)(ws + WS_WB);
  float* out   = (float*)d_out;

  // zero stats + bucket counters (8 KB)
  hipMemsetAsync(d_ws, 0, (size_t)WS_ZERO * sizeof(float), stream);

  prep_fused<<<NPART + NCONV + NYG, 256, 0, stream>>>(
      gc_src, gc_dst, gcur, gedges, Wr1, Wb, x_gene, Wl1, ygene, E);

  gemm_fused<<<NBUCKET, 256, 0, stream>>>(gedges, gcur, ygene, x_cell, Wb,
                                          bl1, preb, stats);

  bn_finalize<<<1, 128, 0, stream>>>(stats);
  bn_apply<<<2048, 256, 0, stream>>>(preb, out, stats);
}

// Round 16
// 89.333 us; speedup vs baseline: 1.1869x; 1.1043x over previous
//
#include <hip/hip_runtime.h>

// Problem constants (from reference)
#define N_CELL 60000
#define N_GENE 4000
#define DIM    128
#define EPS_BN 1e-5f

#define NBUCKET 938            // ceil(60000/64) buckets of 64 cells (= tile)
#define CAP_H   2048           // per-bucket capacity: mean 1600, +11 sigma
#define PBLK_I4 2048           // int4s per partition block (= 8192 edges)
#define NPART   184            // partition blocks
#define NCONV   64             // conv_w blocks
#define NYG     250            // ygene blocks (16 rows each)

// Workspace layout (4-byte words).  Zeroed region = first WS_ZERO words.
//   stats  [512]             @ 0         (sum,sumsq,mu,istd — 128 each)
//   gcur   [1024]            @ 512       (int; per-bucket counters, 938 used)
//   --- end of zeroed region (2048 words) ---
//   preb   [N_CELL*DIM bf16] @ 2048      (3.84M w)  -> ends 3,842,048
//   ygene  [N_GENE*DIM bf16] @ 3,842,048 (256K w)   -> ends 4,098,048
//   gedges [NBUCKET*CAP_H]   @ 4,098,048 (1.92M w)  -> ends 6,019,072
//   Wb     [16384 bf16]      @ 6,019,072 (8192 w)   -> ends 6,027,264 (24.1 MB)
#define WS_STATS  0
#define WS_GCUR   512
#define WS_ZERO   2048
#define WS_PREB   2048
#define WS_YGENE  3842048
#define WS_GEDGE  4098048
#define WS_WB     6019072

typedef __bf16 bf16x8 __attribute__((ext_vector_type(8)));
typedef float  f32x4  __attribute__((ext_vector_type(4)));

__device__ __forceinline__ float bflo(unsigned int u) {
  return __uint_as_float(u << 16);
}
__device__ __forceinline__ float bfhi(unsigned int u) {
  return __uint_as_float(u & 0xFFFF0000u);
}
__device__ __forceinline__ float bf2f(unsigned short u) {
  return __uint_as_float((unsigned int)u << 16);
}
__device__ __forceinline__ unsigned short f2bf(float f) {
  const __bf16 b = (__bf16)f;
  return __builtin_bit_cast(unsigned short, b);
}

#define ACC8(acc, v)                                   \
  do {                                                 \
    acc[0] += bflo((v).x); acc[1] += bfhi((v).x);      \
    acc[2] += bflo((v).y); acc[3] += bfhi((v).y);      \
    acc[4] += bflo((v).z); acc[5] += bfhi((v).z);      \
    acc[6] += bflo((v).w); acc[7] += bfhi((v).w);      \
  } while (0)

// ---------------------------------------------------------------------------
// prep_fused: three independent prep stages in ONE dispatch (R13 version).
//   blocks [0,184)    : partition edges -> 938 bucket regions (64 cells each)
//   blocks [184,248)  : conv_w (Wr fp32 -> fragment-ordered bf16)
//   blocks [248,498)  : ygene = bf16(x_gene @ Wl), 16 rows per block
// ---------------------------------------------------------------------------
__global__ __launch_bounds__(256) void prep_fused(
    const int* __restrict__ src, const int* __restrict__ dst,
    int* __restrict__ gcur, unsigned int* __restrict__ gedges,
    const float* __restrict__ wr, unsigned short* __restrict__ wb,
    const float* __restrict__ xg, const float* __restrict__ wl,
    unsigned short* __restrict__ ygene, int E) {
  __shared__ unsigned int sorted[PBLK_I4 * 4];  // 32 KB
  __shared__ int hist[1024], off[1024];
  __shared__ int cur[1024], gbase[1024];
  __shared__ int sc[256];
  __shared__ int tot;
  const int t = threadIdx.x;

  if (blockIdx.x >= NPART + NCONV) {
    // ---------------- ygene: 16 rows, 256 threads ----------------
    const int bb = blockIdx.x - (NPART + NCONV);
    const int j  = t & 127;
    const int r0 = bb * 16 + (t >> 7) * 8;
    float acc[8] = {};
    for (int k = 0; k < DIM; ++k) {
      const float w = wl[k * DIM + j];
#pragma unroll
      for (int r = 0; r < 8; ++r)
        acc[r] += xg[(size_t)(r0 + r) * DIM + k] * w;
    }
#pragma unroll
    for (int r = 0; r < 8; ++r)
      ygene[(size_t)(r0 + r) * DIM + j] = f2bf(acc[r]);
    return;
  }
  if (blockIdx.x >= NPART) {
    // ---------------- conv_w ----------------
    const int i = (blockIdx.x - NPART) * 256 + t;   // 0..16383
    const int k = i >> 7, j = i & 127;
    const int chunk = (k >> 5) * 8 + (j >> 4);
    const int lane  = ((k >> 3) & 3) * 16 + (j & 15);
    const int e     = k & 7;
    wb[(chunk * 64 + lane) * 8 + e] = f2bf(wr[i]);
    return;
  }

  // ---------------- partition (938 buckets, bucket = dst>>6) ----------------
  hist[t] = 0; hist[256 + t] = 0; hist[512 + t] = 0; hist[768 + t] = 0;
  __syncthreads();

  const int n4    = E >> 2;                 // E divisible by 4 (1.5e6)
  const int base4 = blockIdx.x * PBLK_I4;
  unsigned int pk[32];
#pragma unroll
  for (int k = 0; k < 8; ++k) {
    const int i4 = base4 + k * 256 + t;
    if (i4 < n4) {
      const int4 d4 = ((const int4*)dst)[i4];
      const int4 s4 = ((const int4*)src)[i4];
      pk[k * 4 + 0] = ((unsigned)d4.x << 12) | (unsigned)s4.x;
      pk[k * 4 + 1] = ((unsigned)d4.y << 12) | (unsigned)s4.y;
      pk[k * 4 + 2] = ((unsigned)d4.z << 12) | (unsigned)s4.z;
      pk[k * 4 + 3] = ((unsigned)d4.w << 12) | (unsigned)s4.w;
#pragma unroll
      for (int j = 0; j < 4; ++j)
        atomicAdd(&hist[pk[k * 4 + j] >> 18], 1);   // bucket = dst>>6, <938
    } else {
#pragma unroll
      for (int j = 0; j < 4; ++j) pk[k * 4 + j] = 0xFFFFFFFFu;
    }
  }
  __syncthreads();

  // ---- exclusive scan of hist[0..1023]: quad-sum + Hillis-Steele(256) ----
  const int h0 = hist[4 * t], h1 = hist[4 * t + 1];
  const int h2 = hist[4 * t + 2], h3 = hist[4 * t + 3];
  const int qs = h0 + h1 + h2 + h3;
  sc[t] = qs;
  __syncthreads();
#pragma unroll
  for (int o = 1; o < 256; o <<= 1) {
    const int v = (t >= o) ? sc[t - o] : 0;
    __syncthreads();
    sc[t] += v;
    __syncthreads();
  }
  {
    const int excl = sc[t] - qs;
    off[4 * t]     = excl;
    off[4 * t + 1] = excl + h0;
    off[4 * t + 2] = excl + h0 + h1;
    off[4 * t + 3] = excl + h0 + h1 + h2;
    if (t == 255) tot = sc[255];
  }
  __syncthreads();

  // ---- reserve global ranges, zero local cursors ----
  cur[t] = 0; cur[256 + t] = 0; cur[512 + t] = 0; cur[768 + t] = 0;
  for (int i = t; i < 1024; i += 256)
    gbase[i] = (i < NBUCKET && hist[i] > 0) ? atomicAdd(&gcur[i], hist[i]) : 0;
  __syncthreads();

  // ---- local scatter: registers -> bucket-sorted LDS ----
#pragma unroll
  for (int k = 0; k < 32; ++k) {
    const unsigned int p = pk[k];
    if (p != 0xFFFFFFFFu) {
      const int b   = p >> 18;
      const int pos = atomicAdd(&cur[b], 1);
      sorted[off[b] + pos] = p;
    }
  }
  __syncthreads();

  // ---- coalesced-run write-out ----
  for (int j = t; j < tot; j += 256) {
    const unsigned int p = sorted[j];
    const int b   = p >> 18;
    const int idx = gbase[b] + (j - off[b]);
    if (idx < CAP_H) gedges[(size_t)b * CAP_H + idx] = p;
  }
}

// ---------------------------------------------------------------------------
// gemm_fused, R16 = R13 base (64-cell tile, LDS A-stage — R15 proved the
// global-A variant slower) + deeper gather MLP:
//   - P1a stages gedges via uint4 (2 loads/thread instead of 8)
//   - P2 processes cells in PAIRS with interleaved 2-deep loads -> 4
//     outstanding loads/lane (R13 had 2) and half the per-cell drain
//     bubbles.  Per-cell summation order is bitwise-identical to R13.
// ---------------------------------------------------------------------------
__global__ __launch_bounds__(256) void gemm_fused(
    const unsigned int* __restrict__ gedges, const int* __restrict__ gcur,
    const unsigned short* __restrict__ yb, const float* __restrict__ xc,
    const unsigned short* __restrict__ wb, const float* __restrict__ bl,
    unsigned short* __restrict__ preb, float* __restrict__ stats) {
  // region: [0,8192) u16 = A-stage (16 KB); [8192,10240) u16 = srt (4 KB).
  __shared__ unsigned short region[10240];
  __shared__ unsigned short msg_lds[64 * 136];   // 17.4 KB
  __shared__ int counts[64], coff[64], ccur[64], sc64[64];
  __shared__ float ps[4][32], ps2[4][32];
  unsigned short* a_lds = region;
  unsigned short* srt   = region + 8192;

  const int b    = blockIdx.x;
  const int t    = threadIdx.x;
  const int row0 = b * 64;

  int cnt = gcur[b];
  if (cnt > CAP_H) cnt = CAP_H;

  if (t < 64) { counts[t] = 0; ccur[t] = 0; }
  __syncthreads();

  // ---- P1a: stage edges (uint4) + per-cell histogram ----
  unsigned int e[8];                             // 8*256 = 2048 = CAP_H
  {
    const uint4* gept = (const uint4*)(gedges + (size_t)b * CAP_H);
#pragma unroll
    for (int k = 0; k < 2; ++k) {
      const int i4 = k * 256 + t;                // 512 uint4 = 2048 edges
      const uint4 ev = gept[i4];                 // in-capacity; masked below
      const int j0 = i4 * 4;
      e[k * 4 + 0] = (j0 + 0 < cnt) ? ev.x : 0xFFFFFFFFu;
      e[k * 4 + 1] = (j0 + 1 < cnt) ? ev.y : 0xFFFFFFFFu;
      e[k * 4 + 2] = (j0 + 2 < cnt) ? ev.z : 0xFFFFFFFFu;
      e[k * 4 + 3] = (j0 + 3 < cnt) ? ev.w : 0xFFFFFFFFu;
#pragma unroll
      for (int j = 0; j < 4; ++j)
        if (e[k * 4 + j] != 0xFFFFFFFFu)
          atomicAdd(&counts[(e[k * 4 + j] >> 12) & 63], 1);
    }
  }
  __syncthreads();

  // ---- P1b: exclusive scan of counts[64] ----
  if (t < 64) sc64[t] = counts[t];
  __syncthreads();
#pragma unroll
  for (int o = 1; o < 64; o <<= 1) {
    int v = 0;
    if (t < 64 && t >= o) v = sc64[t - o];
    __syncthreads();
    if (t < 64) sc64[t] += v;
    __syncthreads();
  }
  if (t < 64) coff[t] = sc64[t] - counts[t];
  __syncthreads();

  // ---- P1c: scatter src indices into cell-sorted srt (u16) ----
#pragma unroll
  for (int k = 0; k < 8; ++k) {
    if (e[k] != 0xFFFFFFFFu) {
      const int c   = (e[k] >> 12) & 63;
      const int pos = atomicAdd(&ccur[c], 1);
      srt[coff[c] + pos] = (unsigned short)(e[k] & 0xFFF);
    }
  }
  __syncthreads();

  // ---- P2: bf16 gather, CELL PAIRS; wave w owns cells [w*16, w*16+16) ----
  const int w    = t >> 6;
  const int l    = t & 63;
  const int grp  = l >> 4;                       // edge group 0..3
  const int lsub = l & 15;                       // 8-dim slice
  for (int cp = 0; cp < 8; ++cp) {
    const int c0 = w * 16 + cp * 2;
    const int c1 = c0 + 1;
    // row0+c < 60000 always except possibly last tile rows; 60000%64==?
    // 60000 = 937*64 + 32 -> last bucket has 32 real cells; counts[c]==0 for
    // the rest, so the gather loops are empty and msg writes are to LDS only.
    const int beg0 = coff[c0], num0 = counts[c0];
    const int beg1 = coff[c1], num1 = counts[c1];

    float x0[8] = {}, y0[8] = {}, x1[8] = {}, y1[8] = {};
    int e0 = grp, e1 = grp;

    // interleaved main loop: 4 independent loads in flight
    while (e0 + 4 < num0 && e1 + 4 < num1) {
      const int sA = srt[beg0 + e0];
      const int sB = srt[beg0 + e0 + 4];
      const int sC = srt[beg1 + e1];
      const int sD = srt[beg1 + e1 + 4];
      const uint4 vA = *(const uint4*)(yb + (size_t)sA * DIM + lsub * 8);
      const uint4 vB = *(const uint4*)(yb + (size_t)sB * DIM + lsub * 8);
      const uint4 vC = *(const uint4*)(yb + (size_t)sC * DIM + lsub * 8);
      const uint4 vD = *(const uint4*)(yb + (size_t)sD * DIM + lsub * 8);
      ACC8(x0, vA); ACC8(y0, vB); ACC8(x1, vC); ACC8(y1, vD);
      e0 += 8; e1 += 8;
    }
    // drain cell 0
    for (; e0 + 4 < num0; e0 += 8) {
      const int sA = srt[beg0 + e0];
      const int sB = srt[beg0 + e0 + 4];
      const uint4 vA = *(const uint4*)(yb + (size_t)sA * DIM + lsub * 8);
      const uint4 vB = *(const uint4*)(yb + (size_t)sB * DIM + lsub * 8);
      ACC8(x0, vA); ACC8(y0, vB);
    }
    if (e0 < num0) {
      const int sA = srt[beg0 + e0];
      const uint4 vA = *(const uint4*)(yb + (size_t)sA * DIM + lsub * 8);
      ACC8(x0, vA);
    }
    // drain cell 1
    for (; e1 + 4 < num1; e1 += 8) {
      const int sC = srt[beg1 + e1];
      const int sD = srt[beg1 + e1 + 4];
      const uint4 vC = *(const uint4*)(yb + (size_t)sC * DIM + lsub * 8);
      const uint4 vD = *(const uint4*)(yb + (size_t)sD * DIM + lsub * 8);
      ACC8(x1, vC); ACC8(y1, vD);
    }
    if (e1 < num1) {
      const int sC = srt[beg1 + e1];
      const uint4 vC = *(const uint4*)(yb + (size_t)sC * DIM + lsub * 8);
      ACC8(x1, vC);
    }

    // reduce + write both cells (same order as R13: a0+a1, xor16, xor32)
    float r0[8], r1[8];
#pragma unroll
    for (int d = 0; d < 8; ++d) {
      float s0 = x0[d] + y0[d];
      s0 += __shfl_xor(s0, 16);
      s0 += __shfl_xor(s0, 32);
      r0[d] = s0;
      float s1 = x1[d] + y1[d];
      s1 += __shfl_xor(s1, 16);
      s1 += __shfl_xor(s1, 32);
      r1[d] = s1;
    }
    if (grp == 0) {
      const float ic0 = 1.0f / fmaxf((float)num0, 1.0f);
      const unsigned int a0w =
          ((unsigned int)f2bf(r0[1] * ic0) << 16) | f2bf(r0[0] * ic0);
      const unsigned int a1w =
          ((unsigned int)f2bf(r0[3] * ic0) << 16) | f2bf(r0[2] * ic0);
      const unsigned int a2w =
          ((unsigned int)f2bf(r0[5] * ic0) << 16) | f2bf(r0[4] * ic0);
      const unsigned int a3w =
          ((unsigned int)f2bf(r0[7] * ic0) << 16) | f2bf(r0[6] * ic0);
      *(uint4*)&msg_lds[c0 * 136 + lsub * 8] = make_uint4(a0w, a1w, a2w, a3w);
      const float ic1 = 1.0f / fmaxf((float)num1, 1.0f);
      const unsigned int b0w =
          ((unsigned int)f2bf(r1[1] * ic1) << 16) | f2bf(r1[0] * ic1);
      const unsigned int b1w =
          ((unsigned int)f2bf(r1[3] * ic1) << 16) | f2bf(r1[2] * ic1);
      const unsigned int b2w =
          ((unsigned int)f2bf(r1[5] * ic1) << 16) | f2bf(r1[4] * ic1);
      const unsigned int b3w =
          ((unsigned int)f2bf(r1[7] * ic1) << 16) | f2bf(r1[6] * ic1);
      *(uint4*)&msg_lds[c1 * 136 + lsub * 8] = make_uint4(b0w, b1w, b2w, b3w);
    }
  }

  // ---- P3a: stage A (fp32 -> bf16, XOR-swizzled); srt is dead now ----
  {
    const int row  = t >> 2;
    const int h    = t & 3;
    const int grow = row0 + row;
    const bool ok  = grow < N_CELL;
    const float* xrow = xc + (size_t)grow * DIM;
#pragma unroll
    for (int i = 0; i < 2; ++i) {
      const int kk = h * 32 + i * 16;
      float4 f0, f1, f2, f3;
      if (ok) {
        f0 = *(const float4*)(xrow + kk);
        f1 = *(const float4*)(xrow + kk + 4);
        f2 = *(const float4*)(xrow + kk + 8);
        f3 = *(const float4*)(xrow + kk + 12);
      } else {
        f0 = f1 = f2 = f3 = make_float4(0.f, 0.f, 0.f, 0.f);
      }
      const float fv[16] = {f0.x, f0.y, f0.z, f0.w, f1.x, f1.y, f1.z, f1.w,
                            f2.x, f2.y, f2.z, f2.w, f3.x, f3.y, f3.z, f3.w};
      union { unsigned short u[16]; uint4 q[2]; } pk;
#pragma unroll
      for (int q = 0; q < 16; ++q) pk.u[q] = f2bf(fv[q]);
      const int s0 = ((kk >> 3) + 0) ^ (row & 15);
      const int s1 = ((kk >> 3) + 1) ^ (row & 15);
      *(uint4*)&a_lds[row * 128 + s0 * 8] = pk.q[0];
      *(uint4*)&a_lds[row * 128 + s1 * 8] = pk.q[1];
    }
  }
  __syncthreads();   // A + msg_lds visible to all

  // ---- P3b: MFMA; wave w owns cols [w*32, w*32+32) ----
  const int l15 = l & 15, lq = l >> 4;
  f32x4 acc[4][2];
#pragma unroll
  for (int g = 0; g < 4; ++g)
#pragma unroll
    for (int c = 0; c < 2; ++c) acc[g][c] = (f32x4){0.f, 0.f, 0.f, 0.f};

#pragma unroll
  for (int ks = 0; ks < 4; ++ks) {
    bf16x8 bfr[2];
#pragma unroll
    for (int c = 0; c < 2; ++c) {
      const int cf = w * 2 + c;
      bfr[c] = *(const bf16x8*)(wb + (size_t)(((ks * 8 + cf) * 64 + l) * 8));
    }
    bf16x8 afr[4];
#pragma unroll
    for (int g = 0; g < 4; ++g) {
      const int row = g * 16 + l15;
      const int s   = (ks * 4 + lq) ^ l15;
      afr[g] = *(const bf16x8*)&a_lds[row * 128 + s * 8];
    }
#pragma unroll
    for (int g = 0; g < 4; ++g)
#pragma unroll
      for (int c = 0; c < 2; ++c)
        acc[g][c] = __builtin_amdgcn_mfma_f32_16x16x32_bf16(
            afr[g], bfr[c], acc[g][c], 0, 0, 0);
  }

  // ---- P4: val = acc + msg + bias, in-place into msg_lds; BN sums ----
  float csum[2] = {0.f, 0.f}, csq[2] = {0.f, 0.f};
#pragma unroll
  for (int g = 0; g < 4; ++g) {
#pragma unroll
    for (int c = 0; c < 2; ++c) {
      const int col = (w * 2 + c) * 16 + l15;
      const float bbl = bl[col];
#pragma unroll
      for (int r = 0; r < 4; ++r) {
        const int row  = g * 16 + lq * 4 + r;
        const int grow = row0 + row;
        if (grow < N_CELL) {
          const int idx = row * 136 + col;
          const float val = acc[g][c][r] + bf2f(msg_lds[idx]) + bbl;
          msg_lds[idx] = f2bf(val);
          csum[c] += val;
          csq[c]  += val * val;
        }
      }
    }
  }
#pragma unroll
  for (int c = 0; c < 2; ++c) {
    csum[c] += __shfl_xor(csum[c], 16);
    csum[c] += __shfl_xor(csum[c], 32);
    csq[c]  += __shfl_xor(csq[c], 16);
    csq[c]  += __shfl_xor(csq[c], 32);
  }
  if (lq == 0) {
#pragma unroll
    for (int c = 0; c < 2; ++c) {
      ps[w][c * 16 + l15]  = csum[c];   // col = w*32 + c*16 + l15
      ps2[w][c * 16 + l15] = csq[c];
    }
  }
  __syncthreads();

  // ---- P5: vectorized store msg_lds -> preb; BN atomics ----
  {
    const int grow = row0 + l;
    if (grow < N_CELL) {
      unsigned short* prow = preb + (size_t)grow * DIM + w * 32;
      const unsigned short* mrow = msg_lds + l * 136 + w * 32;
#pragma unroll
      for (int i = 0; i < 4; ++i)
        *(uint4*)(prow + i * 8) = *(const uint4*)(mrow + i * 8);
    }
    const int which = t >> 7;          // 0: sum, 1: sumsq
    const int col   = t & 127;
    const int wi    = col >> 5;
    const int idx   = col & 31;
    const float v = which ? ps2[wi][idx] : ps[wi][idx];
    unsafeAtomicAdd(&stats[t], v);     // t in [0,256)
  }
}

// ---------------------------------------------------------------------------
// bn_finalize: mu / inv_std from accumulated sums (1 block, ~2 us)
// ---------------------------------------------------------------------------
__global__ __launch_bounds__(128) void bn_finalize(float* __restrict__ stats) {
  const int j = threadIdx.x;
  const float mu  = stats[j] / (float)N_CELL;
  const float var = stats[128 + j] / (float)N_CELL - mu * mu;
  stats[256 + j] = mu;
  stats[384 + j] = rsqrtf(var + EPS_BN);
}

// ---------------------------------------------------------------------------
// bn_apply: read bf16 pre (L2/L3-hot), write fp32 out
// ---------------------------------------------------------------------------
__global__ __launch_bounds__(256) void bn_apply(
    const unsigned short* __restrict__ preb, float* __restrict__ out,
    const float* __restrict__ stats) {
  const size_t total = (size_t)N_CELL * DIM / 8;
  const size_t step  = (size_t)gridDim.x * blockDim.x;
  for (size_t i = (size_t)blockIdx.x * blockDim.x + threadIdx.x; i < total;
       i += step) {
    const uint4 v = ((const uint4*)preb)[i];
    const int col = (int)((i * 8) & (DIM - 1));
    const float* mu = stats + 256 + col;
    const float* is = stats + 384 + col;
    float4 o0, o1;
    o0.x = (bflo(v.x) - mu[0]) * is[0];
    o0.y = (bfhi(v.x) - mu[1]) * is[1];
    o0.z = (bflo(v.y) - mu[2]) * is[2];
    o0.w = (bfhi(v.y) - mu[3]) * is[3];
    o1.x = (bflo(v.z) - mu[4]) * is[4];
    o1.y = (bfhi(v.z) - mu[5]) * is[5];
    o1.z = (bflo(v.w) - mu[6]) * is[6];
    o1.w = (bfhi(v.w) - mu[7]) * is[7];
    *(float4*)(out + i * 8)     = o0;
    *(float4*)(out + i * 8 + 4) = o1;
  }
}

// ---------------------------------------------------------------------------
extern "C" void kernel_launch(void* const* d_in, const int* in_sizes, int n_in,
                              void* d_out, int out_size, void* d_ws,
                              size_t ws_size, hipStream_t stream) {
  const float* x_cell = (const float*)d_in[0];
  const float* x_gene = (const float*)d_in[1];
  const float* Wl_gc  = (const float*)d_in[2];
  const float* bl_gc  = (const float*)d_in[3];
  const float* Wr_gc  = (const float*)d_in[4];
  // d_in[5..7] (cg weights) are dead: the gene branch never feeds the output.
  const int* gc_src = (const int*)d_in[8];
  const int* gc_dst = (const int*)d_in[9];
  const int  E      = in_sizes[8];

  const float* Wl1 = Wl_gc + DIM * DIM;   // layer 1 (last)
  const float* bl1 = bl_gc + DIM;
  const float* Wr1 = Wr_gc + DIM * DIM;

  float* ws    = (float*)d_ws;
  float* stats = ws + WS_STATS;
  int*   gcur  = (int*)(ws + WS_GCUR);
  unsigned short* preb   = (unsigned short*)(ws + WS_PREB);
  unsigned short* ygene  = (unsigned short*)(ws + WS_YGENE);
  unsigned int*   gedges = (unsigned int*)(ws + WS_GEDGE);
  unsigned short* Wb     = (unsigned short*)(ws + WS_WB);
  float* out   = (float*)d_out;

  // zero stats + bucket counters (8 KB)
  hipMemsetAsync(d_ws, 0, (size_t)WS_ZERO * sizeof(float), stream);

  prep_fused<<<NPART + NCONV + NYG, 256, 0, stream>>>(
      gc_src, gc_dst, gcur, gedges, Wr1, Wb, x_gene, Wl1, ygene, E);

  gemm_fused<<<NBUCKET, 256, 0, stream>>>(gedges, gcur, ygene, x_cell, Wb,
                                          bl1, preb, stats);

  bn_finalize<<<1, 128, 0, stream>>>(stats);
  bn_apply<<<2048, 256, 0, stream>>>(preb, out, stats);
}